// Round 3
// baseline (1278.365 us; speedup 1.0000x reference)
//
#include <hip/hip_runtime.h>

typedef unsigned short bf16_t;
typedef __attribute__((ext_vector_type(8))) __bf16 bf16x8;
typedef __attribute__((ext_vector_type(4))) float f32x4;

__device__ __forceinline__ float bf2f(unsigned v) { return __uint_as_float(v << 16); }
__device__ __forceinline__ bf16_t f2bf(float f) {
  unsigned u = __float_as_uint(f);
  return (bf16_t)((u + 0x7fffu + ((u >> 16) & 1u)) >> 16);
}
__device__ __forceinline__ unsigned pack2(float a, float b) {
  return (unsigned)f2bf(a) | ((unsigned)f2bf(b) << 16);
}

// ---------- exclusive scan of name_lens ----------
__global__ __launch_bounds__(256) void scan_lens(const int* __restrict__ lens,
                                                 int* __restrict__ offs,
                                                 int* __restrict__ Mact) {
  __shared__ int wsum[4];
  const int t = threadIdx.x;
  int v[16]; int s = 0;
#pragma unroll
  for (int i = 0; i < 16; i++) { v[i] = lens[t * 16 + i]; s += v[i]; }
  const int lane = t & 63, w = t >> 6;
  int x = s;
#pragma unroll
  for (int o = 1; o < 64; o <<= 1) {
    int y = __shfl_up(x, o);
    if (lane >= o) x += y;
  }
  if (lane == 63) wsum[w] = x;
  __syncthreads();
  int base = 0;
  for (int i = 0; i < w; i++) base += wsum[i];
  int run = base + x - s;
#pragma unroll
  for (int i = 0; i < 16; i++) { offs[t * 16 + i] = run; run += v[i]; }
  if (t == 255) Mact[0] = run;
}

// ---------- fused f32 -> bf16 convert of all plain weights ----------
__global__ void cvt_all(const float* __restrict__ mha_in_w, const float* __restrict__ mha_out_w,
                        const float* __restrict__ bott_w, const float* __restrict__ enc_out_w,
                        const float* __restrict__ enc_ff1_w, const float* __restrict__ enc_ff2_w,
                        bf16_t* __restrict__ w_qkv, bf16_t* __restrict__ w_out,
                        bf16_t* __restrict__ w_bott, bf16_t* __restrict__ w_enco,
                        bf16_t* __restrict__ w_ff1, bf16_t* __restrict__ w_ff2) {
  long i = (long)blockIdx.x * blockDim.x + threadIdx.x;
  const float* src; bf16_t* dst; long j;
  if (i < 442368L)        { src = mha_in_w;  dst = w_qkv;  j = i; }
  else if (i < 589824L)   { src = mha_out_w; dst = w_out;  j = i - 442368L; }
  else if (i < 851968L)   { src = bott_w;    dst = w_bott; j = i - 589824L; }
  else if (i < 1900544L)  { src = enc_out_w; dst = w_enco; j = i - 851968L; }
  else if (i < 3997696L)  { src = enc_ff1_w; dst = w_ff1;  j = i - 1900544L; }
  else if (i < 6094848L)  { src = enc_ff2_w; dst = w_ff2;  j = i - 3997696L; }
  else return;
  float4 v = ((const float4*)src)[j];
  ((uint2*)dst)[j] = make_uint2(pack2(v.x, v.y), pack2(v.z, v.w));
}

// ---------- transpose-convert V-slice of enc_in_w: dst[l][n][k] = Wv[l][k][n] ----------
__global__ __launch_bounds__(256) void cvt_encvT(const float* __restrict__ enc_in_w,
                                                 bf16_t* __restrict__ dst) {
  __shared__ float lt[64][65];
  const int t = threadIdx.x;
  const int tx = t & 15, ty = t >> 4;
  const int n0 = blockIdx.x * 64, k0 = blockIdx.y * 64, l = blockIdx.z;
  const float* src = enc_in_w + (size_t)l * 3 * 1024 * 1024 + 2 * 1024 * 1024;
#pragma unroll
  for (int p = 0; p < 4; p++) {
    int kr = p * 16 + ty;
    float4 v = *(const float4*)(src + (size_t)(k0 + kr) * 1024 + n0 + tx * 4);
    lt[kr][tx * 4 + 0] = v.x; lt[kr][tx * 4 + 1] = v.y;
    lt[kr][tx * 4 + 2] = v.z; lt[kr][tx * 4 + 3] = v.w;
  }
  __syncthreads();
  bf16_t* d = dst + (size_t)l * 1024 * 1024;
#pragma unroll
  for (int p = 0; p < 4; p++) {
    int nr = p * 16 + ty;
    float a = lt[tx * 4 + 0][nr], b = lt[tx * 4 + 1][nr];
    float c = lt[tx * 4 + 2][nr], e = lt[tx * 4 + 3][nr];
    *(uint2*)(d + (size_t)(n0 + nr) * 1024 + k0 + tx * 4) = make_uint2(pack2(a, b), pack2(c, e));
  }
}

// ---------- fused bias: b_vo[l][m] = enc_out_w[l][m,:] . enc_in_b[l][2048:] + enc_out_b[l][m] ----------
__global__ __launch_bounds__(256) void bias_vo(const float* __restrict__ enc_out_w,
                                               const float* __restrict__ enc_in_b,
                                               const float* __restrict__ enc_out_b,
                                               float* __restrict__ b_vo) {
  const int t = threadIdx.x, lane = t & 63, w = t >> 6;
  const int m = blockIdx.x * 4 + w, l = blockIdx.y;
  const float* wr = enc_out_w + (size_t)l * 1024 * 1024 + (size_t)m * 1024;
  const float* bv = enc_in_b + l * 3072 + 2048;
  float acc = 0.f;
#pragma unroll
  for (int i = 0; i < 16; i++) acc += wr[lane + i * 64] * bv[lane + i * 64];
#pragma unroll
  for (int o = 32; o > 0; o >>= 1) acc += __shfl_down(acc, o);
  if (lane == 0) b_vo[l * 1024 + m] = acc + enc_out_b[l * 1024 + m];
}

// ---------- compacted embedding gather ----------
__global__ void gather_emb_c(const int* __restrict__ tok, const int* __restrict__ lens,
                             const int* __restrict__ offs, const float* __restrict__ wte,
                             bf16_t* __restrict__ emb) {
  long i = (long)blockIdx.x * blockDim.x + threadIdx.x;
  if (i >= 65536L * 192L) return;
  long nl = i / 192; int cg = (int)(i % 192);
  int n = (int)(nl >> 4), l = (int)(nl & 15);
  if (l >= lens[n]) return;
  long ro = (long)offs[n] + l;
  int t = tok[nl];
  float4 v = *(const float4*)(wte + (long)t * 768 + cg * 4);
  ((uint2*)emb)[ro * 192 + cg] = make_uint2(pack2(v.x, v.y), pack2(v.z, v.w));
}

// ---------- x_feats cast into x[:,0:256] + lens->float ----------
__global__ void xfeat_lenf(const float* __restrict__ xf, const int* __restrict__ lens,
                           bf16_t* __restrict__ x, float* __restrict__ lenf) {
  long i = (long)blockIdx.x * blockDim.x + threadIdx.x;
  if (i < 4096) lenf[i] = (float)lens[i];
  if (i >= 4096L * 64L) return;
  int row = (int)(i >> 6); int c4 = (int)(i & 63) * 4;
  float4 v = *(const float4*)(xf + (long)row * 256 + c4);
  *(uint2*)(x + (long)row * 1024 + c4) = make_uint2(pack2(v.x, v.y), pack2(v.z, v.w));
}

__device__ __forceinline__ void async16(const void* g, void* l) {
  __builtin_amdgcn_global_load_lds((const __attribute__((address_space(1))) void*)g,
                                   (__attribute__((address_space(3))) void*)l, 16, 0, 0);
}

// ---------- 128x128 MFMA GEMM (large-M QKV): C = A @ W^T + bias ----------
__global__ __launch_bounds__(256, 2) void gemm_bt(
    const bf16_t* __restrict__ A, const bf16_t* __restrict__ W,
    const float* __restrict__ bias, bf16_t* __restrict__ C,
    int K, int ldc, const int* __restrict__ Mp) {
  const int m0 = blockIdx.y * 128;
  if (m0 >= *Mp) return;
  __shared__ __attribute__((aligned(16))) bf16_t As[128 * 32];
  __shared__ __attribute__((aligned(16))) bf16_t Bs[128 * 32];
  const int t = threadIdx.x;
  const int n0 = blockIdx.x * 128;
  const int lane = t & 63;
  const int wr = t >> 7, wc = (t >> 6) & 1;
  const int quad = lane >> 4, r16 = lane & 15;

  f32x4 acc[4][4] = {};

  const int c0 = t, c1 = t + 256;
  const int row0 = c0 >> 2, kp0 = (c0 & 3) << 3;
  const int row1 = c1 >> 2, kp1 = (c1 & 3) << 3;
  bf16_t* lA0 = As + (size_t)(c0 & ~63) * 8;
  bf16_t* lA1 = As + (size_t)(c1 & ~63) * 8;
  bf16_t* lB0 = Bs + (size_t)(c0 & ~63) * 8;
  bf16_t* lB1 = Bs + (size_t)(c1 & ~63) * 8;
  const bf16_t* Ab = A + (size_t)m0 * K;
  const bf16_t* Wb = W + (size_t)n0 * K;

  for (int k0 = 0; k0 < K; k0 += 32) {
    __syncthreads();
    async16(Ab + (size_t)row0 * K + k0 + kp0, lA0);
    async16(Ab + (size_t)row1 * K + k0 + kp1, lA1);
    async16(Wb + (size_t)row0 * K + k0 + kp0, lB0);
    async16(Wb + (size_t)row1 * K + k0 + kp1, lB1);
    __syncthreads();
    bf16x8 af[4], bfr[4];
#pragma unroll
    for (int i = 0; i < 4; i++) {
      af[i]  = *(const bf16x8*)(As + (wr * 64 + i * 16 + r16) * 32 + quad * 8);
      bfr[i] = *(const bf16x8*)(Bs + (wc * 64 + i * 16 + r16) * 32 + quad * 8);
    }
#pragma unroll
    for (int i = 0; i < 4; i++)
#pragma unroll
      for (int j = 0; j < 4; j++)
        acc[i][j] = __builtin_amdgcn_mfma_f32_16x16x32_bf16(af[i], bfr[j], acc[i][j], 0, 0, 0);
  }

  const int colb = n0 + wc * 64, rowb = m0 + wr * 64;
#pragma unroll
  for (int j = 0; j < 4; j++) {
    int col = colb + j * 16 + r16;
    float bv = bias ? bias[col] : 0.0f;
#pragma unroll
    for (int i = 0; i < 4; i++) {
      int rbase = rowb + i * 16 + quad * 4;
#pragma unroll
      for (int r = 0; r < 4; r++) {
        int row = rbase + r;
        C[(size_t)row * ldc + col] = f2bf(acc[i][j][r] + bv);
      }
    }
  }
}

// ---------- 128x64 MFMA GEMM (encoder shapes; batched via z) ----------
// C = A @ W^T + bias [+ rowscale[m]*bias term]; optional ReLU.
template <bool RELU>
__global__ __launch_bounds__(256, 4) void gemm_bn(
    const bf16_t* __restrict__ A, const bf16_t* __restrict__ W,
    const float* __restrict__ bias, const float* __restrict__ rowscale,
    bf16_t* __restrict__ C, int K, int ldc, long sA, long sW, long sC) {
  __shared__ __attribute__((aligned(16))) bf16_t As[128 * 32];
  __shared__ __attribute__((aligned(16))) bf16_t Bs[64 * 32];
  const int z = blockIdx.z;
  A += (size_t)z * sA; W += (size_t)z * sW; C += (size_t)z * sC;
  const int t = threadIdx.x;
  const int m0 = blockIdx.y * 128, n0 = blockIdx.x * 64;
  const int lane = t & 63;
  const int wr = t >> 7, wc = (t >> 6) & 1;
  const int quad = lane >> 4, r16 = lane & 15;

  f32x4 acc[4][2] = {};

  const int c0 = t, c1 = t + 256;
  const int rowA0 = c0 >> 2, kpA0 = (c0 & 3) << 3;
  const int rowA1 = c1 >> 2, kpA1 = (c1 & 3) << 3;
  const int rowB = t >> 2, kpB = (t & 3) << 3;
  bf16_t* lA0 = As + (size_t)(c0 & ~63) * 8;
  bf16_t* lA1 = As + (size_t)(c1 & ~63) * 8;
  bf16_t* lB  = Bs + (size_t)(t & ~63) * 8;
  const bf16_t* Ab = A + (size_t)m0 * K;
  const bf16_t* Wb = W + (size_t)n0 * K;

  for (int k0 = 0; k0 < K; k0 += 32) {
    __syncthreads();
    async16(Ab + (size_t)rowA0 * K + k0 + kpA0, lA0);
    async16(Ab + (size_t)rowA1 * K + k0 + kpA1, lA1);
    async16(Wb + (size_t)rowB * K + k0 + kpB, lB);
    __syncthreads();
    bf16x8 af[4], bfr[2];
#pragma unroll
    for (int i = 0; i < 4; i++)
      af[i] = *(const bf16x8*)(As + (wr * 64 + i * 16 + r16) * 32 + quad * 8);
#pragma unroll
    for (int j = 0; j < 2; j++)
      bfr[j] = *(const bf16x8*)(Bs + (wc * 32 + j * 16 + r16) * 32 + quad * 8);
#pragma unroll
    for (int i = 0; i < 4; i++)
#pragma unroll
      for (int j = 0; j < 2; j++)
        acc[i][j] = __builtin_amdgcn_mfma_f32_16x16x32_bf16(af[i], bfr[j], acc[i][j], 0, 0, 0);
  }

  const int colb = n0 + wc * 32, rowb = m0 + wr * 64;
#pragma unroll
  for (int j = 0; j < 2; j++) {
    int col = colb + j * 16 + r16;
    float bv = bias ? bias[col] : 0.0f;
#pragma unroll
    for (int i = 0; i < 4; i++) {
      int rbase = rowb + i * 16 + quad * 4;
#pragma unroll
      for (int r = 0; r < 4; r++) {
        int row = rbase + r;
        float sc = rowscale ? rowscale[row] : 1.0f;
        float v = acc[i][j][r] + bv * sc;
        if (RELU) v = fmaxf(v, 0.0f);
        C[(size_t)row * ldc + col] = f2bf(v);
      }
    }
  }
}

// ---------- name attention on compacted qkv ----------
__global__ __launch_bounds__(64) void attn_name(const bf16_t* __restrict__ qkv,
                                                const int* __restrict__ lens,
                                                const int* __restrict__ offs,
                                                bf16_t* __restrict__ s) {
  const int n = blockIdx.x, h = blockIdx.y;
  const int lane = threadIdx.x;
  __shared__ unsigned short qs[16][208];
  __shared__ unsigned short ks[16][208];
  __shared__ unsigned short vs[16][208];
  __shared__ float ps[16][16];
  __shared__ float wj[16];
  const int len = lens[n];
  const bf16_t* base = qkv + (size_t)offs[n] * 2304 + h * 192;
  for (int g = lane; g < len * 48; g += 64) {
    int row = g / 48, c4 = (g % 48) * 4;
    const bf16_t* p = base + (size_t)row * 2304 + c4;
    uint2 a;
    a = *(const uint2*)p;
    *(unsigned*)&qs[row][c4] = a.x; *(unsigned*)&qs[row][c4 + 2] = a.y;
    a = *(const uint2*)(p + 768);
    *(unsigned*)&ks[row][c4] = a.x; *(unsigned*)&ks[row][c4 + 2] = a.y;
    a = *(const uint2*)(p + 1536);
    *(unsigned*)&vs[row][c4] = a.x; *(unsigned*)&vs[row][c4 + 2] = a.y;
  }
  __syncthreads();
  {
    const int l = lane >> 2, j0 = (lane & 3) * 4;
    float s0 = 0, s1 = 0, s2 = 0, s3 = 0;
    for (int d = 0; d < 192; d++) {
      float q = bf2f(qs[l][d]);
      s0 += q * bf2f(ks[j0 + 0][d]);
      s1 += q * bf2f(ks[j0 + 1][d]);
      s2 += q * bf2f(ks[j0 + 2][d]);
      s3 += q * bf2f(ks[j0 + 3][d]);
    }
    const float sc = 0.07216878f;  // 1/sqrt(192)
    ps[l][j0 + 0] = s0 * sc; ps[l][j0 + 1] = s1 * sc;
    ps[l][j0 + 2] = s2 * sc; ps[l][j0 + 3] = s3 * sc;
  }
  __syncthreads();
  if (lane < 16) {
    float m = -1e30f;
    for (int j = 0; j < len; j++) m = fmaxf(m, ps[lane][j]);
    float sum = 0.f;
    for (int j = 0; j < len; j++) sum += __expf(ps[lane][j] - m);
    float inv = 1.0f / sum;
    for (int j = 0; j < 16; j++) ps[lane][j] = (j < len) ? __expf(ps[lane][j] - m) * inv : 0.0f;
  }
  __syncthreads();
  if (lane < 16) {
    float a = 0.f;
    for (int l2 = 0; l2 < len; l2++) a += ps[l2][lane];
    wj[lane] = a;
  }
  __syncthreads();
  for (int d = lane; d < 192; d += 64) {
    float a = 0.f;
    for (int j = 0; j < len; j++) a += wj[j] * bf2f(vs[j][d]);
    s[(size_t)n * 768 + h * 192 + d] = f2bf(a);
  }
}

// ---------- residual + layernorm (in place on h) ----------
__global__ __launch_bounds__(256) void ln_res(bf16_t* __restrict__ h, const bf16_t* __restrict__ d,
                                              const float* __restrict__ g, const float* __restrict__ b) {
  const int n = blockIdx.x, t = threadIdx.x;
  __shared__ float s1[4], s2[4];
  bf16_t* hr = h + (size_t)n * 1024;
  const bf16_t* dr = d + (size_t)n * 1024;
  float x[4];
  float sum = 0.f, ss = 0.f;
#pragma unroll
  for (int i = 0; i < 4; i++) {
    int c = t + i * 256;
    float v = bf2f(hr[c]) + bf2f(dr[c]);
    x[i] = v; sum += v; ss += v * v;
  }
#pragma unroll
  for (int o = 32; o > 0; o >>= 1) { sum += __shfl_down(sum, o); ss += __shfl_down(ss, o); }
  if ((t & 63) == 0) { s1[t >> 6] = sum; s2[t >> 6] = ss; }
  __syncthreads();
  sum = s1[0] + s1[1] + s1[2] + s1[3];
  ss  = s2[0] + s2[1] + s2[2] + s2[3];
  const float mean = sum * (1.0f / 1024.0f);
  const float var = ss * (1.0f / 1024.0f) - mean * mean;
  const float rstd = rsqrtf(var + 1e-5f);
#pragma unroll
  for (int i = 0; i < 4; i++) {
    int c = t + i * 256;
    hr[c] = f2bf((x[i] - mean) * rstd * g[c] + b[c]);
  }
}

// ---------- classifier head ----------
__global__ __launch_bounds__(256) void cls_head(const bf16_t* __restrict__ h,
                                                const float* __restrict__ cw,
                                                const float* __restrict__ cb,
                                                float* __restrict__ out) {
  const int n = blockIdx.x, t = threadIdx.x, wave = t >> 6, lane = t & 63;
  const bf16_t* hr = h + (size_t)n * 1024;
  for (int c = wave; c < 16; c += 4) {
    const float* wr = cw + c * 1024;
    float acc = 0.f;
    for (int i = lane; i < 1024; i += 64) acc += bf2f(hr[i]) * wr[i];
#pragma unroll
    for (int o = 32; o > 0; o >>= 1) acc += __shfl_down(acc, o);
    if (lane == 0) out[(size_t)n * 16 + c] = acc + cb[c];
  }
}

extern "C" void kernel_launch(void* const* d_in, const int* in_sizes, int n_in,
                              void* d_out, int out_size, void* d_ws, size_t ws_size,
                              hipStream_t stream) {
  (void)in_sizes; (void)n_in; (void)out_size; (void)ws_size;
  const int* name_tokens = (const int*)d_in[0];
  const int* name_lens   = (const int*)d_in[1];
  const float* x_feats   = (const float*)d_in[2];
  const float* wte       = (const float*)d_in[3];
  const float* mha_in_w  = (const float*)d_in[4];
  const float* mha_in_b  = (const float*)d_in[5];
  const float* mha_out_w = (const float*)d_in[6];
  const float* mha_out_b = (const float*)d_in[7];
  const float* bott_w    = (const float*)d_in[8];
  const float* bott_b    = (const float*)d_in[9];
  const float* enc_in_w  = (const float*)d_in[10];
  const float* enc_in_b  = (const float*)d_in[11];
  const float* enc_out_w = (const float*)d_in[12];
  const float* enc_out_b = (const float*)d_in[13];
  const float* enc_ln1_g = (const float*)d_in[14];
  const float* enc_ln1_b = (const float*)d_in[15];
  const float* enc_ln2_g = (const float*)d_in[16];
  const float* enc_ln2_b = (const float*)d_in[17];
  const float* enc_ff1_w = (const float*)d_in[18];
  const float* enc_ff1_b = (const float*)d_in[19];
  const float* enc_ff2_w = (const float*)d_in[20];
  const float* enc_ff2_b = (const float*)d_in[21];
  const float* cls_w     = (const float*)d_in[22];
  const float* cls_b     = (const float*)d_in[23];
  float* out = (float*)d_out;

  char* base = (char*)d_ws;
  size_t off = 0;
  auto alloc = [&](size_t bytes) -> char* {
    char* p = base + off;
    off = (off + bytes + 255) & ~(size_t)255;
    return p;
  };
  bf16_t* w_qkv   = (bf16_t*)alloc((size_t)2304 * 768 * 2);
  bf16_t* w_out   = (bf16_t*)alloc((size_t)768 * 768 * 2);
  bf16_t* w_bott  = (bf16_t*)alloc((size_t)1024 * 1024 * 2);
  bf16_t* w_enco  = (bf16_t*)alloc((size_t)4 * 1024 * 1024 * 2);
  bf16_t* w_encvT = (bf16_t*)alloc((size_t)4 * 1024 * 1024 * 2);
  bf16_t* w_vo    = (bf16_t*)alloc((size_t)4 * 1024 * 1024 * 2);
  bf16_t* w_ff1   = (bf16_t*)alloc((size_t)4 * 2048 * 1024 * 2);
  bf16_t* w_ff2   = (bf16_t*)alloc((size_t)4 * 1024 * 2048 * 2);
  float*  b_vo    = (float*)alloc((size_t)4 * 1024 * 4);
  float*  lenf    = (float*)alloc((size_t)4096 * 4);
  int*    offs    = (int*)alloc((size_t)4096 * 4);
  int*    Mact    = (int*)alloc((size_t)256);
  char* reuse = alloc((size_t)65536 * 768 * 2);  // emb region, reused after QKV GEMM
  bf16_t* emb = (bf16_t*)reuse;
  bf16_t* s_  = (bf16_t*)reuse;                            // 4096x768
  bf16_t* x_  = (bf16_t*)(reuse + 6291456);                // 4096x1024
  bf16_t* h_  = (bf16_t*)(reuse + 6291456 + 8388608);      // 4096x1024
  bf16_t* v_  = (bf16_t*)(reuse + 6291456 + 2 * 8388608);  // 4096x1024
  bf16_t* a_  = (bf16_t*)(reuse + 6291456 + 3 * 8388608);  // 4096x1024
  bf16_t* f1_ = (bf16_t*)(reuse + 6291456 + 4 * 8388608);  // 4096x2048
  bf16_t* qkv = (bf16_t*)alloc((size_t)65536 * 2304 * 2);

  dim3 b256(256);
  const float* nof = nullptr;

  scan_lens<<<dim3(1), b256, 0, stream>>>(name_lens, offs, Mact);
  cvt_all<<<dim3(23808), b256, 0, stream>>>(mha_in_w, mha_out_w, bott_w, enc_out_w,
                                            enc_ff1_w, enc_ff2_w,
                                            w_qkv, w_out, w_bott, w_enco, w_ff1, w_ff2);
  cvt_encvT<<<dim3(16, 16, 4), b256, 0, stream>>>(enc_in_w, w_encvT);
  bias_vo<<<dim3(256, 4), b256, 0, stream>>>(enc_out_w, enc_in_b, enc_out_b, b_vo);

  // stage A (compacted rows)
  gather_emb_c<<<dim3(49152), b256, 0, stream>>>(name_tokens, name_lens, offs, wte, emb);
  gemm_bt<<<dim3(18, 512), b256, 0, stream>>>(emb, w_qkv, mha_in_b, qkv, 768, 2304, Mact);
  xfeat_lenf<<<dim3(1024), b256, 0, stream>>>(x_feats, name_lens, x_, lenf);
  attn_name<<<dim3(4096, 4), dim3(64), 0, stream>>>(qkv, name_lens, offs, s_);

  // w_vo[l] = w_enco[l] @ w_encvT[l]^T  (= Wo @ Wv), batched over 4 layers
  gemm_bn<false><<<dim3(16, 8, 4), b256, 0, stream>>>(
      w_enco, w_encvT, nof, nof, w_vo, 1024, 1024,
      1024L * 1024, 1024L * 1024, 1024L * 1024);

  // name out-proj: x[:,256:] = s @ w_out^T + lenf*mha_out_b
  gemm_bn<false><<<dim3(12, 32, 1), b256, 0, stream>>>(
      s_, w_out, mha_out_b, lenf, x_ + 256, 768, 1024, 0, 0, 0);
  // bottleneck: h = x @ bott_w^T + bott_b
  gemm_bn<false><<<dim3(16, 32, 1), b256, 0, stream>>>(
      x_, w_bott, bott_b, nof, h_, 1024, 1024, 0, 0, 0);

  // encoder layers (seq len 1; V+O fused into w_vo)
  for (int l = 0; l < 4; l++) {
    gemm_bn<false><<<dim3(16, 32, 1), b256, 0, stream>>>(
        h_, w_vo + (size_t)l * 1024 * 1024, b_vo + l * 1024, nof, a_, 1024, 1024, 0, 0, 0);
    ln_res<<<dim3(4096), b256, 0, stream>>>(h_, a_, enc_ln1_g + l * 1024, enc_ln1_b + l * 1024);
    gemm_bn<true><<<dim3(32, 32, 1), b256, 0, stream>>>(
        h_, w_ff1 + (size_t)l * 2048 * 1024, enc_ff1_b + l * 2048, nof, f1_, 1024, 2048, 0, 0, 0);
    gemm_bn<false><<<dim3(16, 32, 1), b256, 0, stream>>>(
        f1_, w_ff2 + (size_t)l * 1024 * 2048, enc_ff2_b + l * 1024, nof, v_, 2048, 1024, 0, 0, 0);
    ln_res<<<dim3(4096), b256, 0, stream>>>(h_, v_, enc_ln2_g + l * 1024, enc_ln2_b + l * 1024);
  }
  cls_head<<<dim3(4096), b256, 0, stream>>>(h_, cls_w, cls_b, out);
}